// Round 1
// baseline (2728.571 us; speedup 1.0000x reference)
//
#include <hip/hip_runtime.h>
#include <hip/hip_bf16.h>
#include <math.h>

// Problem constants
#define BATCH 4
#define CDIM 192
#define C3 576
#define HWDIM 65536   // 256*256
#define IMGW 256
#define NHEADS 4
#define HDIM 48       // head_dim

// ---------------------------------------------------------------------------
// K1/K6: C[M][HW] = A[M][192] * X[192][HW], fp32, tile 64(M) x 128(N) x 32(K)
// 256 threads, each computes 8 oc x 4 px.
// ---------------------------------------------------------------------------
__global__ __launch_bounds__(256) void gemm_k192(
    const float* __restrict__ A,   // [M][192]
    const float* __restrict__ X,   // [192][HWDIM]
    float* __restrict__ C)         // [M][HWDIM]
{
    __shared__ __align__(16) float Wt[32][68];    // k-major: Wt[kk][oc_l]
    __shared__ __align__(16) float Xs[32][132];   // Xs[kk][px_l]
    const int tid = threadIdx.x;
    const int px0 = blockIdx.x * 128;
    const int oc0 = blockIdx.y * 64;
    const int ocg = tid >> 5;      // 0..7  -> oc rows [ocg*8, +8)
    const int pxg = tid & 31;      // 0..31 -> px cols [pxg*4, +4)

    float acc[8][4];
#pragma unroll
    for (int i = 0; i < 8; ++i)
#pragma unroll
        for (int j = 0; j < 4; ++j) acc[i][j] = 0.f;

    for (int k0 = 0; k0 < 192; k0 += 32) {
        // A tile: 64 oc x 32 k, each thread loads 8 consecutive k of one row
        {
            const int ocl = tid >> 2;
            const int kk0 = (tid & 3) << 3;
            const float* src = A + (size_t)(oc0 + ocl) * 192 + k0 + kk0;
            float4 a0 = *(const float4*)src;
            float4 a1 = *(const float4*)(src + 4);
            Wt[kk0 + 0][ocl] = a0.x; Wt[kk0 + 1][ocl] = a0.y;
            Wt[kk0 + 2][ocl] = a0.z; Wt[kk0 + 3][ocl] = a0.w;
            Wt[kk0 + 4][ocl] = a1.x; Wt[kk0 + 5][ocl] = a1.y;
            Wt[kk0 + 6][ocl] = a1.z; Wt[kk0 + 7][ocl] = a1.w;
        }
        // X tile: 32 k x 128 px = 1024 float4, 4 per thread
#pragma unroll
        for (int i = 0; i < 4; ++i) {
            const int idx = tid + (i << 8);
            const int row = idx >> 5;
            const int c4  = (idx & 31) << 2;
            *(float4*)&Xs[row][c4] =
                *(const float4*)(X + (size_t)(k0 + row) * HWDIM + px0 + c4);
        }
        __syncthreads();
#pragma unroll
        for (int kk = 0; kk < 32; ++kk) {
            float4 xv = *(const float4*)&Xs[kk][pxg << 2];
            float4 w0 = *(const float4*)&Wt[kk][ocg << 3];
            float4 w1 = *(const float4*)&Wt[kk][(ocg << 3) + 4];
            float w[8] = {w0.x, w0.y, w0.z, w0.w, w1.x, w1.y, w1.z, w1.w};
            float xx[4] = {xv.x, xv.y, xv.z, xv.w};
#pragma unroll
            for (int i = 0; i < 8; ++i)
#pragma unroll
                for (int j = 0; j < 4; ++j)
                    acc[i][j] = fmaf(w[i], xx[j], acc[i][j]);
        }
        __syncthreads();
    }
#pragma unroll
    for (int i = 0; i < 8; ++i) {
        const int oc = oc0 + (ocg << 3) + i;
        *(float4*)(C + (size_t)oc * HWDIM + px0 + (pxg << 2)) =
            make_float4(acc[i][0], acc[i][1], acc[i][2], acc[i][3]);
    }
}

// ---------------------------------------------------------------------------
// K2: depthwise 3x3, SAME zero padding. One block per (channel, 8-row group),
// 256 threads = one per column (image width = 256).
// ---------------------------------------------------------------------------
__global__ __launch_bounds__(256) void dw3x3(
    const float* __restrict__ in,   // [576][256][256]
    const float* __restrict__ wdw,  // [576][9]
    float* __restrict__ out)        // [576][256][256]
{
    const int ch = blockIdx.x;
    const int y0 = blockIdx.y * 8;
    const int x  = threadIdx.x;
    __shared__ float rows[10][258];
    const float* inc = in + (size_t)ch * HWDIM;
#pragma unroll
    for (int r = 0; r < 10; ++r) {
        const int y = y0 - 1 + r;
        rows[r][x + 1] = (y >= 0 && y < IMGW) ? inc[y * IMGW + x] : 0.f;
    }
    if (x < 10) { rows[x][0] = 0.f; rows[x][257] = 0.f; }
    __syncthreads();
    float w[9];
#pragma unroll
    for (int i = 0; i < 9; ++i) w[i] = wdw[ch * 9 + i];
#pragma unroll
    for (int r = 0; r < 8; ++r) {
        float s = 0.f;
#pragma unroll
        for (int dy = 0; dy < 3; ++dy)
#pragma unroll
            for (int dx = 0; dx < 3; ++dx)
                s = fmaf(rows[r + dy][x + dx], w[dy * 3 + dx], s);
        out[(size_t)ch * HWDIM + (y0 + r) * IMGW + x] = s;
    }
}

// ---------------------------------------------------------------------------
// K3: Gram S[d][e] = sum_n q[d,n]*k[e,n] plus row sums-of-squares (norms),
// for one (head, 256-px chunk). 64 threads; active 48 own a 6x8 (d,e) tile.
// Accumulate to global via fp32 atomics. Sb layout per head: [48*48 S][48 nq][48 nk]
// ---------------------------------------------------------------------------
__global__ __launch_bounds__(64) void gram(
    const float* __restrict__ qkdw,  // qkv_dw base (q: ch 0..191, k: ch 192..383)
    float* __restrict__ Sb)          // [4][2400] for this batch
{
    const int chunk = blockIdx.x;    // 0..255 -> 256 px each
    const int h = blockIdx.y;
    const int p0 = chunk << 8;
    const float* qbase = qkdw + (size_t)(h * HDIM) * HWDIM;
    const float* kbase = qkdw + (size_t)(192 + h * HDIM) * HWDIM;
    __shared__ float qks[96][65];    // rows 0..47 = q, 48..95 = k; pad 65
    const int t = threadIdx.x;
    const int te = t % 6;            // e group (8 e's)
    const int td = t / 6;            // d group (6 d's); active if td<8
    const bool act = (t < 48);

    float acc[6][8];
#pragma unroll
    for (int i = 0; i < 6; ++i)
#pragma unroll
        for (int j = 0; j < 8; ++j) acc[i][j] = 0.f;
    float nq[6] = {0.f, 0.f, 0.f, 0.f, 0.f, 0.f};
    float nk[8] = {0.f, 0.f, 0.f, 0.f, 0.f, 0.f, 0.f, 0.f};

    for (int sc = 0; sc < 4; ++sc) {
        const int pb = p0 + (sc << 6);   // 64-px sub-chunk
        // stage 96 rows x 64 px
#pragma unroll
        for (int i = 0; i < 24; ++i) {
            const int idx4 = t + (i << 6);        // 0..1535
            const int row  = idx4 >> 4;           // 0..95
            const int col  = (idx4 & 15) << 2;
            const float* src = (row < 48) ? (qbase + (size_t)row * HWDIM)
                                          : (kbase + (size_t)(row - 48) * HWDIM);
            float4 v = *(const float4*)(src + pb + col);
            qks[row][col + 0] = v.x; qks[row][col + 1] = v.y;
            qks[row][col + 2] = v.z; qks[row][col + 3] = v.w;
        }
        __syncthreads();
        if (act) {
            for (int p = 0; p < 64; ++p) {
                float qv[6], kv[8];
#pragma unroll
                for (int i = 0; i < 6; ++i) qv[i] = qks[td * 6 + i][p];
#pragma unroll
                for (int j = 0; j < 8; ++j) kv[j] = qks[48 + te * 8 + j][p];
#pragma unroll
                for (int i = 0; i < 6; ++i)
#pragma unroll
                    for (int j = 0; j < 8; ++j)
                        acc[i][j] = fmaf(qv[i], kv[j], acc[i][j]);
                if (te == 0) {
#pragma unroll
                    for (int i = 0; i < 6; ++i) nq[i] = fmaf(qv[i], qv[i], nq[i]);
                }
                if (td == 0) {
#pragma unroll
                    for (int j = 0; j < 8; ++j) nk[j] = fmaf(kv[j], kv[j], nk[j]);
                }
            }
        }
        __syncthreads();
    }
    if (act) {
        float* S = Sb + h * 2400;
#pragma unroll
        for (int i = 0; i < 6; ++i)
#pragma unroll
            for (int j = 0; j < 8; ++j)
                atomicAdd(&S[(td * 6 + i) * 48 + (te * 8 + j)], acc[i][j]);
        if (te == 0) {
#pragma unroll
            for (int i = 0; i < 6; ++i) atomicAdd(&S[2304 + td * 6 + i], nq[i]);
        }
        if (td == 0) {
#pragma unroll
            for (int j = 0; j < 8; ++j) atomicAdd(&S[2352 + te * 8 + j], nk[j]);
        }
    }
}

// ---------------------------------------------------------------------------
// K4: per batch - normalize Gram, softmax (over e), fold proj:
//     W2[co][h*48+e] = sum_d proj[co][h*48+d] * attn[h][d][e]
// One block, 256 threads.
// ---------------------------------------------------------------------------
__global__ __launch_bounds__(256) void attn_w2(
    const float* __restrict__ S,     // [4][2400] this batch
    const float* __restrict__ proj,  // [192][192]
    const float* __restrict__ temp,  // [4]
    float* __restrict__ W2)          // [192][192]
{
    __shared__ float attn[NHEADS][HDIM][HDIM];   // 36.9 KB
    __shared__ float nqs[NHEADS][HDIM], nks[NHEADS][HDIM];
    const int t = threadIdx.x;
    for (int idx = t; idx < NHEADS * 96; idx += 256) {
        const int h = idx / 96;
        const int r = idx % 96;
        float v = sqrtf(S[h * 2400 + 2304 + r]);
        v = fmaxf(v, 1e-12f);
        if (r < 48) nqs[h][r] = v; else nks[h][r - 48] = v;
    }
    __syncthreads();
    if (t < NHEADS * HDIM) {
        const int h = t / HDIM, d = t % HDIM;
        const float tp = temp[h];
        const float inq = 1.0f / nqs[h][d];
        float row[48];
        float mx = -1e30f;
#pragma unroll
        for (int e = 0; e < 48; ++e) {
            row[e] = S[h * 2400 + d * 48 + e] * inq / nks[h][e] * tp;
            mx = fmaxf(mx, row[e]);
        }
        float sum = 0.f;
#pragma unroll
        for (int e = 0; e < 48; ++e) {
            row[e] = expf(row[e] - mx);
            sum += row[e];
        }
        const float isum = 1.0f / sum;
#pragma unroll
        for (int e = 0; e < 48; ++e) attn[h][d][e] = row[e] * isum;
    }
    __syncthreads();
    for (int idx = t; idx < 192 * 192; idx += 256) {
        const int co = idx / 192, he = idx % 192;
        const int h = he / 48, e = he % 48;
        const float* pr = proj + co * 192 + h * 48;
        float s = 0.f;
#pragma unroll
        for (int d = 0; d < 48; ++d) s = fmaf(pr[d], attn[h][d][e], s);
        W2[co * 192 + he] = s;
    }
}

__global__ void zerof(float* __restrict__ p, int n)
{
    const int i = blockIdx.x * 256 + threadIdx.x;
    if (i < n) p[i] = 0.f;
}

// ---------------------------------------------------------------------------
extern "C" void kernel_launch(void* const* d_in, const int* in_sizes, int n_in,
                              void* d_out, int out_size, void* d_ws, size_t ws_size,
                              hipStream_t stream)
{
    const float* x      = (const float*)d_in[0];  // [4][192][65536]
    const float* qkv_w  = (const float*)d_in[1];  // [576][192]
    const float* dw_w   = (const float*)d_in[2];  // [576][9]
    const float* proj_w = (const float*)d_in[3];  // [192][192]
    const float* temp   = (const float*)d_in[4];  // [4]
    float* out = (float*)d_out;
    float* ws  = (float*)d_ws;

    float* qkv_tmp = ws;                               // 576*65536 floats
    float* qkv_dw  = ws + (size_t)37748736;            // 576*65536 floats
    float* S_all   = ws + (size_t)75497472;            // 4*4*2400 = 38400 floats
    float* W2      = ws + (size_t)75535872;            // 192*192 floats (per-batch reuse)

    zerof<<<150, 256, 0, stream>>>(S_all, 38400);

    for (int b = 0; b < BATCH; ++b) {
        const float* xb  = x   + (size_t)b * CDIM * HWDIM;
        float*       ob  = out + (size_t)b * CDIM * HWDIM;
        float*       Sb  = S_all + (size_t)b * 9600;

        // 1) qkv = qkv_w @ x  (576x192 * 192xHW)
        gemm_k192<<<dim3(512, 9), 256, 0, stream>>>(qkv_w, xb, qkv_tmp);
        // 2) depthwise 3x3
        dw3x3<<<dim3(576, 32), 256, 0, stream>>>(qkv_tmp, dw_w, qkv_dw);
        // 3) Gram + norms for q,k
        gram<<<dim3(256, 4), 64, 0, stream>>>(qkv_dw, Sb);
        // 4) softmax + fold projection into W2
        attn_w2<<<1, 256, 0, stream>>>(Sb, proj_w, temp, W2);
        // 5) out = W2 @ v  (192x192 * 192xHW)
        gemm_k192<<<dim3(512, 3), 256, 0, stream>>>(W2, qkv_dw + (size_t)384 * HWDIM, ob);
    }
}

// Round 4
// 1256.057 us; speedup vs baseline: 2.1723x; 2.1723x over previous
//
#include <hip/hip_runtime.h>
#include <hip/hip_bf16.h>

#define BATCH 4
#define CDIM 192
#define HWDIM 65536   // 256*256
#define IMGW 256
#define NHEADS 4
#define HDIM 48
#define KPAD 200      // LDS k-dim padding: stride 400B = 100 banks == 4 mod 32

typedef __attribute__((ext_vector_type(8))) short short8;   // 8 bf16 (4 VGPR)
typedef __attribute__((ext_vector_type(4))) float f32x4;

#define MFMA16(a, b, c) __builtin_amdgcn_mfma_f32_16x16x32_bf16(a, b, c, 0, 0, 0)

__device__ __forceinline__ ushort f2bf(float x) {
    unsigned u = __float_as_uint(x);
    unsigned r = u + 0x7FFFu + ((u >> 16) & 1u);   // RNE
    return (ushort)(r >> 16);
}
__device__ __forceinline__ float bf2f(ushort h) {
    return __uint_as_float(((unsigned)h) << 16);
}

// ---------------------------------------------------------------------------
// Split fp32 array into bf16 hi/lo planes (small weight arrays)
// ---------------------------------------------------------------------------
__global__ __launch_bounds__(256) void wsplit(
    const float* __restrict__ in, ushort* __restrict__ hi, ushort* __restrict__ lo, int n)
{
    int i = blockIdx.x * 256 + threadIdx.x;
    if (i < n) {
        float x = in[i];
        ushort h = f2bf(x);
        hi[i] = h;
        lo[i] = f2bf(x - bf2f(h));
    }
}

// ---------------------------------------------------------------------------
// Staged MFMA GEMM (bf16x3): C[M][HW] = A[M][192] * X[192][HW], X fp32 native.
// Block: 256 thr = 4 waves on M (48 rows each); BM=192, BN=64, K=192 staged
// whole into LDS (n-major, hi/lo planes) with on-the-fly fp32->bf16 split.
// SPLITOUT: rows <384 -> bf16 qk_out, rows >=384 -> fp32 v_out; else plain fp32.
// ---------------------------------------------------------------------------
template<bool SPLITOUT>
__global__ __launch_bounds__(256) void gemm_staged(
    const ushort* __restrict__ Ahi, const ushort* __restrict__ Alo,  // [M][192]
    const float*  __restrict__ X,   // [192][HWDIM] fp32
    ushort* __restrict__ qk_out,    // [384][65536]  (SPLITOUT)
    float*  __restrict__ v_out,     // [192][65536]  (SPLITOUT)
    float*  __restrict__ plain)     // [192][65536]  (!SPLITOUT)
{
    __shared__ __align__(16) ushort Bh[64][KPAD];
    __shared__ __align__(16) ushort Bl[64][KPAD];

    const int t    = threadIdx.x;
    const int lane = t & 63;
    const int wave = t >> 6;
    const int n0   = blockIdx.x * 64;
    const int mw   = blockIdx.y * 192 + wave * 48;
    const int ar   = lane & 15;          // row within 16-tile
    const int kg   = (lane >> 4) * 8;    // k offset within 32-chunk

    // ---- stage X[0:192][n0:n0+64] -> Bh/Bl (n-major), fp32 -> hi/lo bf16 ----
    {
        const int n4 = (t & 15) * 4;         // 4 consecutive px
        const int kb = (t >> 4) * 2;         // even k row within 32-group
#pragma unroll
        for (int pass = 0; pass < 6; ++pass) {
            const int k2 = pass * 32 + kb;
            float4 f0 = *(const float4*)(X + (size_t)k2 * HWDIM + n0 + n4);
            float4 f1 = *(const float4*)(X + (size_t)(k2 + 1) * HWDIM + n0 + n4);
            const float* a0 = (const float*)&f0;
            const float* a1 = (const float*)&f1;
#pragma unroll
            for (int i = 0; i < 4; ++i) {
                ushort h0 = f2bf(a0[i]);
                ushort l0 = f2bf(a0[i] - bf2f(h0));
                ushort h1 = f2bf(a1[i]);
                ushort l1 = f2bf(a1[i] - bf2f(h1));
                *(unsigned*)&Bh[n4 + i][k2] = (unsigned)h0 | ((unsigned)h1 << 16);
                *(unsigned*)&Bl[n4 + i][k2] = (unsigned)l0 | ((unsigned)l1 << 16);
            }
        }
    }
    __syncthreads();

    // ---- main loop: 6 k-steps, no further barriers ----
    f32x4 acc[3][4];
#pragma unroll
    for (int i = 0; i < 3; ++i)
#pragma unroll
        for (int j = 0; j < 4; ++j) { f32x4 z = {0.f, 0.f, 0.f, 0.f}; acc[i][j] = z; }

    const ushort* aph = Ahi + (size_t)(mw + ar) * 192 + kg;
    const ushort* apl = Alo + (size_t)(mw + ar) * 192 + kg;

#pragma unroll
    for (int k0 = 0; k0 < 192; k0 += 32) {
        short8 ah[3], al[3], bh[4], bl[4];
#pragma unroll
        for (int i = 0; i < 3; ++i) {
            ah[i] = *reinterpret_cast<const short8*>(aph + i * 16 * 192 + k0);
            al[i] = *reinterpret_cast<const short8*>(apl + i * 16 * 192 + k0);
        }
#pragma unroll
        for (int j = 0; j < 4; ++j) {
            bh[j] = *reinterpret_cast<const short8*>(&Bh[j * 16 + ar][k0 + kg]);
            bl[j] = *reinterpret_cast<const short8*>(&Bl[j * 16 + ar][k0 + kg]);
        }
#pragma unroll
        for (int i = 0; i < 3; ++i)
#pragma unroll
            for (int j = 0; j < 4; ++j) {
                acc[i][j] = MFMA16(ah[i], bh[j], acc[i][j]);
                acc[i][j] = MFMA16(ah[i], bl[j], acc[i][j]);
                acc[i][j] = MFMA16(al[i], bh[j], acc[i][j]);
            }
    }

    // ---- epilogue: C/D layout col=lane&15, row=(lane>>4)*4+r ----
    const int rr = (lane >> 4) * 4;
#pragma unroll
    for (int i = 0; i < 3; ++i)
#pragma unroll
        for (int j = 0; j < 4; ++j) {
            const int n = n0 + j * 16 + (lane & 15);
#pragma unroll
            for (int r = 0; r < 4; ++r) {
                const int mm = mw + i * 16 + rr + r;
                const float v = acc[i][j][r];
                if (SPLITOUT) {
                    if (mm < 384) qk_out[(size_t)mm * HWDIM + n] = f2bf(v);
                    else          v_out[(size_t)(mm - 384) * HWDIM + n] = v;
                } else {
                    plain[(size_t)mm * HWDIM + n] = v;
                }
            }
        }
}

// ---------------------------------------------------------------------------
// Depthwise 3x3 SAME, bf16 in -> bf16 out (q,k channels)
// ---------------------------------------------------------------------------
__global__ __launch_bounds__(256) void dw3x3_bf(
    const ushort* __restrict__ in,   // [384][65536]
    const float* __restrict__ wdw,   // dw_w (ch-indexed, 9 per ch)
    ushort* __restrict__ out)
{
    const int ch = blockIdx.x;
    const int y0 = blockIdx.y * 8;
    const int x  = threadIdx.x;
    __shared__ float rows[10][258];
    const ushort* inc = in + (size_t)ch * HWDIM;
#pragma unroll
    for (int r = 0; r < 10; ++r) {
        const int y = y0 - 1 + r;
        rows[r][x + 1] = (y >= 0 && y < IMGW) ? bf2f(inc[y * IMGW + x]) : 0.f;
    }
    if (x < 10) { rows[x][0] = 0.f; rows[x][257] = 0.f; }
    __syncthreads();
    float w[9];
#pragma unroll
    for (int i = 0; i < 9; ++i) w[i] = wdw[ch * 9 + i];
#pragma unroll
    for (int r = 0; r < 8; ++r) {
        float s = 0.f;
#pragma unroll
        for (int dy = 0; dy < 3; ++dy)
#pragma unroll
            for (int dx = 0; dx < 3; ++dx)
                s = fmaf(rows[r + dy][x + dx], w[dy * 3 + dx], s);
        out[(size_t)ch * HWDIM + (y0 + r) * IMGW + x] = f2bf(s);
    }
}

// fp32 in -> fp32 out (v channels)
__global__ __launch_bounds__(256) void dw3x3_f32(
    const float* __restrict__ in,    // [192][65536]
    const float* __restrict__ wdw,   // dw_w + 384*9
    float* __restrict__ out)
{
    const int ch = blockIdx.x;
    const int y0 = blockIdx.y * 8;
    const int x  = threadIdx.x;
    __shared__ float rows[10][258];
    const float* inc = in + (size_t)ch * HWDIM;
#pragma unroll
    for (int r = 0; r < 10; ++r) {
        const int y = y0 - 1 + r;
        rows[r][x + 1] = (y >= 0 && y < IMGW) ? inc[y * IMGW + x] : 0.f;
    }
    if (x < 10) { rows[x][0] = 0.f; rows[x][257] = 0.f; }
    __syncthreads();
    float w[9];
#pragma unroll
    for (int i = 0; i < 9; ++i) w[i] = wdw[ch * 9 + i];
#pragma unroll
    for (int r = 0; r < 8; ++r) {
        float s = 0.f;
#pragma unroll
        for (int dy = 0; dy < 3; ++dy)
#pragma unroll
            for (int dx = 0; dx < 3; ++dx)
                s = fmaf(rows[r + dy][x + dx], w[dy * 3 + dx], s);
        out[(size_t)ch * HWDIM + (y0 + r) * IMGW + x] = s;
    }
}

// ---------------------------------------------------------------------------
// Gram via MFMA (plain bf16): S[d][e] = sum_n q[d,n]*k[e,n], plus row norms
// accumulated from the same fragments. grid(32 chunks, 4 heads), 256 thr.
// Sb layout per head: [48*48 S][48 nq][48 nk]
// ---------------------------------------------------------------------------
__global__ __launch_bounds__(256) void gram_mfma(
    const ushort* __restrict__ qk,   // [384][65536] bf16 (post-dw)
    float* __restrict__ Sb)          // [4][2400] this batch
{
    const int h = blockIdx.y;
    const int lane = threadIdx.x & 63;
    const int wave = threadIdx.x >> 6;
    const int nbase = blockIdx.x * 2048 + wave * 512;
    const ushort* q0  = qk + (size_t)(h * HDIM) * HWDIM;
    const ushort* k0p = qk + (size_t)(192 + h * HDIM) * HWDIM;
    const int ar = lane & 15;
    const int kg = (lane >> 4) * 8;

    f32x4 acc[3][3];
#pragma unroll
    for (int i = 0; i < 3; ++i)
#pragma unroll
        for (int j = 0; j < 3; ++j) { f32x4 z = {0.f, 0.f, 0.f, 0.f}; acc[i][j] = z; }
    float sq[3] = {0.f, 0.f, 0.f}, sk[3] = {0.f, 0.f, 0.f};

    for (int ks = 0; ks < 512; ks += 32) {
        const int n = nbase + ks + kg;
        short8 qa[3], ka[3];
#pragma unroll
        for (int i = 0; i < 3; ++i) {
            qa[i] = *reinterpret_cast<const short8*>(q0  + (size_t)(i * 16 + ar) * HWDIM + n);
            ka[i] = *reinterpret_cast<const short8*>(k0p + (size_t)(i * 16 + ar) * HWDIM + n);
        }
#pragma unroll
        for (int i = 0; i < 3; ++i)
#pragma unroll
            for (int e = 0; e < 8; ++e) {
                float fq = bf2f((ushort)qa[i][e]);
                float fk = bf2f((ushort)ka[i][e]);
                sq[i] = fmaf(fq, fq, sq[i]);
                sk[i] = fmaf(fk, fk, sk[i]);
            }
#pragma unroll
        for (int i = 0; i < 3; ++i)
#pragma unroll
            for (int j = 0; j < 3; ++j)
                acc[i][j] = MFMA16(qa[i], ka[j], acc[i][j]);
    }

    __shared__ float S_l[2400];
    for (int t = threadIdx.x; t < 2400; t += 256) S_l[t] = 0.f;
    __syncthreads();
    const int rr = (lane >> 4) * 4;
#pragma unroll
    for (int i = 0; i < 3; ++i)
#pragma unroll
        for (int j = 0; j < 3; ++j)
#pragma unroll
            for (int r = 0; r < 4; ++r)
                atomicAdd(&S_l[(i * 16 + rr + r) * 48 + (j * 16 + ar)], acc[i][j][r]);
    // reduce norms across the 4 k-groups holding the same row
#pragma unroll
    for (int i = 0; i < 3; ++i) {
        sq[i] += __shfl_xor(sq[i], 16); sq[i] += __shfl_xor(sq[i], 32);
        sk[i] += __shfl_xor(sk[i], 16); sk[i] += __shfl_xor(sk[i], 32);
    }
    if ((lane >> 4) == 0) {
#pragma unroll
        for (int i = 0; i < 3; ++i) {
            atomicAdd(&S_l[2304 + i * 16 + ar], sq[i]);
            atomicAdd(&S_l[2352 + i * 16 + ar], sk[i]);
        }
    }
    __syncthreads();
    float* Sg = Sb + h * 2400;
    for (int t = threadIdx.x; t < 2400; t += 256) atomicAdd(&Sg[t], S_l[t]);
}

// ---------------------------------------------------------------------------
// Normalize Gram, softmax over e, fold proj into W2 (bf16 hi/lo out).
// grid(4): block handles 48 output channels. All blocks recompute attn (cheap).
// ---------------------------------------------------------------------------
__global__ __launch_bounds__(256) void attn_w2(
    const float* __restrict__ S,     // [4][2400] this batch
    const float* __restrict__ proj,  // [192][192]
    const float* __restrict__ temp,  // [4]
    ushort* __restrict__ W2hi,       // [192][192]
    ushort* __restrict__ W2lo)
{
    __shared__ float attn[NHEADS][HDIM][HDIM];
    __shared__ float nqs[NHEADS][HDIM], nks[NHEADS][HDIM];
    const int t = threadIdx.x;
    const int co0 = blockIdx.x * 48;
    for (int idx = t; idx < NHEADS * 96; idx += 256) {
        const int h = idx / 96, r = idx % 96;
        float v = sqrtf(S[h * 2400 + 2304 + r]);
        v = fmaxf(v, 1e-12f);
        if (r < 48) nqs[h][r] = v; else nks[h][r - 48] = v;
    }
    __syncthreads();
    if (t < NHEADS * HDIM) {
        const int h = t / HDIM, d = t % HDIM;
        const float tp  = temp[h];
        const float inq = 1.0f / nqs[h][d];
        float row[48];
        float mx = -1e30f;
#pragma unroll
        for (int e = 0; e < 48; ++e) {
            row[e] = S[h * 2400 + d * 48 + e] * inq / nks[h][e] * tp;
            mx = fmaxf(mx, row[e]);
        }
        float sum = 0.f;
#pragma unroll
        for (int e = 0; e < 48; ++e) { row[e] = expf(row[e] - mx); sum += row[e]; }
        const float isum = 1.0f / sum;
#pragma unroll
        for (int e = 0; e < 48; ++e) attn[h][d][e] = row[e] * isum;
    }
    __syncthreads();
    for (int idx = t; idx < 48 * 192; idx += 256) {
        const int co = co0 + idx / 192, he = idx % 192;
        const int h = he / 48, e = he % 48;
        const float* pr = proj + co * 192 + h * 48;
        float s = 0.f;
#pragma unroll
        for (int d = 0; d < 48; ++d) s = fmaf(pr[d], attn[h][d][e], s);
        ushort hh = f2bf(s);
        W2hi[co * 192 + he] = hh;
        W2lo[co * 192 + he] = f2bf(s - bf2f(hh));
    }
}

__global__ void zerof(float* __restrict__ p, int n)
{
    const int i = blockIdx.x * 256 + threadIdx.x;
    if (i < n) p[i] = 0.f;
}

// ---------------------------------------------------------------------------
extern "C" void kernel_launch(void* const* d_in, const int* in_sizes, int n_in,
                              void* d_out, int out_size, void* d_ws, size_t ws_size,
                              hipStream_t stream)
{
    const float* x      = (const float*)d_in[0];  // [4][192][65536]
    const float* qkv_w  = (const float*)d_in[1];  // [576][192]
    const float* dw_w   = (const float*)d_in[2];  // [576][9]
    const float* proj_w = (const float*)d_in[3];  // [192][192]
    const float* temp   = (const float*)d_in[4];  // [4]
    float* out = (float*)d_out;

    char* w = (char*)d_ws;
    ushort* qk_pre = (ushort*)w;                 w += (size_t)384 * HWDIM * 2;   // 50.3 MB
    float*  v_pre  = (float*)w;                  w += (size_t)192 * HWDIM * 4;   // 50.3 MB
    ushort* qk_dw  = (ushort*)w;                 w += (size_t)384 * HWDIM * 2;   // 50.3 MB
    float*  v_dw   = (float*)w;                  w += (size_t)192 * HWDIM * 4;   // 50.3 MB
    ushort* A1hi   = (ushort*)w;                 w += (size_t)576 * 192 * 2;
    ushort* A1lo   = (ushort*)w;                 w += (size_t)576 * 192 * 2;
    ushort* W2hi   = (ushort*)w;                 w += (size_t)192 * 192 * 2;
    ushort* W2lo   = (ushort*)w;                 w += (size_t)192 * 192 * 2;
    float*  S_all  = (float*)w;                  w += (size_t)BATCH * 4 * 2400 * 4;

    zerof<<<150, 256, 0, stream>>>(S_all, BATCH * 4 * 2400);
    wsplit<<<(576 * 192 + 255) / 256, 256, 0, stream>>>(qkv_w, A1hi, A1lo, 576 * 192);

    for (int b = 0; b < BATCH; ++b) {
        const float* xb = x   + (size_t)b * CDIM * HWDIM;
        float*       ob = out + (size_t)b * CDIM * HWDIM;
        float*       Sb = S_all + (size_t)b * 4 * 2400;

        // 1) qkv 1x1 conv (bf16x3 MFMA, LDS-staged from native x layout)
        gemm_staged<true><<<dim3(1024, 3), 256, 0, stream>>>(
            A1hi, A1lo, xb, qk_pre, v_pre, nullptr);
        // 2) depthwise 3x3
        dw3x3_bf <<<dim3(384, 32), 256, 0, stream>>>(qk_pre, dw_w, qk_dw);
        dw3x3_f32<<<dim3(192, 32), 256, 0, stream>>>(v_pre, dw_w + 384 * 9, v_dw);
        // 3) Gram + norms (bf16 MFMA)
        gram_mfma<<<dim3(32, 4), 256, 0, stream>>>(qk_dw, Sb);
        // 4) softmax + fold projection
        attn_w2<<<4, 256, 0, stream>>>(Sb, proj_w, temp, W2hi, W2lo);
        // 5) out = W2 @ v (bf16x3 MFMA, LDS-staged from native v layout)
        gemm_staged<false><<<dim3(1024, 1), 256, 0, stream>>>(
            W2hi, W2lo, v_dw, nullptr, nullptr, ob);
    }
}

// Round 8
// 1078.298 us; speedup vs baseline: 2.5304x; 1.1649x over previous
//
#include <hip/hip_runtime.h>
#include <hip/hip_bf16.h>

#define BATCH 4
#define ZPAIR 2       // batches per launch (pair)
#define CDIM 192
#define HWDIM 65536   // 256*256
#define IMGW 256
#define NHEADS 4
#define HDIM 48
#define KPAD 200      // LDS row stride (ushorts); rows 400B -> b128-aligned

typedef __attribute__((ext_vector_type(8))) short short8;   // 8 bf16 (4 VGPR)
typedef __attribute__((ext_vector_type(4))) float f32x4;

#define MFMA16(a, b, c) __builtin_amdgcn_mfma_f32_16x16x32_bf16(a, b, c, 0, 0, 0)

__device__ __forceinline__ ushort f2bf(float x) {
    unsigned u = __float_as_uint(x);
    unsigned r = u + 0x7FFFu + ((u >> 16) & 1u);   // RNE
    return (ushort)(r >> 16);
}
__device__ __forceinline__ float bf2f(ushort h) {
    return __uint_as_float(((unsigned)h) << 16);
}

// ---------------------------------------------------------------------------
// Split fp32 array into bf16 hi/lo planes (small weight arrays)
// ---------------------------------------------------------------------------
__global__ __launch_bounds__(256) void wsplit(
    const float* __restrict__ in, ushort* __restrict__ hi, ushort* __restrict__ lo, int n)
{
    int i = blockIdx.x * 256 + threadIdx.x;
    if (i < n) {
        float x = in[i];
        ushort h = f2bf(x);
        hi[i] = h;
        lo[i] = f2bf(x - bf2f(h));
    }
}

// ---------------------------------------------------------------------------
// Staged MFMA GEMM (bf16x3): C[M][HW] = A[M][192] * X[192][HW], X fp32 native.
// 256 thr = 4 waves on M (48 rows each); BM=192, BN=64, K=192 staged whole
// into LDS with on-the-fly fp32->bf16 hi/lo split.
// LDS layout: flat [row][KPAD] with 16B-block XOR swizzle:
//   physical block = (k>>3) ^ ((row>>2)&7)  -> staging ds_write_b32 are
//   2-way (free); frag ds_read_b128 stay aligned+contiguous (swizzle moves
//   whole 16B blocks and reads are exactly 16B blocks).
// blockIdx.z = batch within pair. zAStride: A-plane stride per z (0 = shared).
// ---------------------------------------------------------------------------
template<bool SPLITOUT>
__global__ __launch_bounds__(256) void gemm_staged(
    const ushort* __restrict__ Ahi, const ushort* __restrict__ Alo,  // [M][192]
    const float*  __restrict__ X,   // [z][192][HWDIM] fp32
    ushort* __restrict__ qk_out,    // [z][384][HWDIM]  (SPLITOUT)
    float*  __restrict__ v_out,     // [z][192][HWDIM]  (SPLITOUT)
    float*  __restrict__ plain,     // [z][192][HWDIM]  (!SPLITOUT)
    int zAStride)
{
    __shared__ __align__(16) ushort Bh[64 * KPAD];
    __shared__ __align__(16) ushort Bl[64 * KPAD];

    const int t    = threadIdx.x;
    const int z    = blockIdx.z;
    const int lane = t & 63;
    const int wave = t >> 6;
    const int n0   = blockIdx.x * 64;
    const int mw   = blockIdx.y * 192 + wave * 48;
    const int ar   = lane & 15;          // row within 16-tile
    const int kg   = (lane >> 4) * 8;    // k offset within 32-chunk

    const float* Xz = X + (size_t)z * CDIM * HWDIM;

    // ---- stage X[0:192][n0:n0+64] -> Bh/Bl, fp32 -> hi/lo bf16, swizzled ----
    {
        const int n4 = (t & 15) * 4;         // 4 consecutive px (rows in LDS)
        const int kb = (t >> 4) * 2;         // even k row within 32-group
#pragma unroll
        for (int pass = 0; pass < 6; ++pass) {
            const int k2 = pass * 32 + kb;
            float4 f0 = *(const float4*)(Xz + (size_t)k2 * HWDIM + n0 + n4);
            float4 f1 = *(const float4*)(Xz + (size_t)(k2 + 1) * HWDIM + n0 + n4);
            const float* a0 = (const float*)&f0;
            const float* a1 = (const float*)&f1;
            const int cb = k2 >> 3;
            const int ki = k2 & 7;
#pragma unroll
            for (int i = 0; i < 4; ++i) {
                const int row = n4 + i;
                const int off = row * KPAD + ((cb ^ ((row >> 2) & 7)) << 3) + ki;
                ushort h0 = f2bf(a0[i]);
                ushort l0 = f2bf(a0[i] - bf2f(h0));
                ushort h1 = f2bf(a1[i]);
                ushort l1 = f2bf(a1[i] - bf2f(h1));
                *(unsigned*)&Bh[off] = (unsigned)h0 | ((unsigned)h1 << 16);
                *(unsigned*)&Bl[off] = (unsigned)l0 | ((unsigned)l1 << 16);
            }
        }
    }
    __syncthreads();

    // ---- main loop: 6 k-steps, no further barriers ----
    f32x4 acc[3][4];
#pragma unroll
    for (int i = 0; i < 3; ++i)
#pragma unroll
        for (int j = 0; j < 4; ++j) { f32x4 zz = {0.f, 0.f, 0.f, 0.f}; acc[i][j] = zz; }

    const ushort* aph = Ahi + (size_t)z * zAStride + (size_t)(mw + ar) * 192 + kg;
    const ushort* apl = Alo + (size_t)z * zAStride + (size_t)(mw + ar) * 192 + kg;

#pragma unroll
    for (int k0 = 0; k0 < 192; k0 += 32) {
        short8 ah[3], al[3], bh[4], bl[4];
#pragma unroll
        for (int i = 0; i < 3; ++i) {
            ah[i] = *reinterpret_cast<const short8*>(aph + i * 16 * 192 + k0);
            al[i] = *reinterpret_cast<const short8*>(apl + i * 16 * 192 + k0);
        }
        const int cb = (k0 + kg) >> 3;
#pragma unroll
        for (int j = 0; j < 4; ++j) {
            const int row = j * 16 + ar;
            const int off = row * KPAD + ((cb ^ ((row >> 2) & 7)) << 3);
            bh[j] = *reinterpret_cast<const short8*>(&Bh[off]);
            bl[j] = *reinterpret_cast<const short8*>(&Bl[off]);
        }
#pragma unroll
        for (int i = 0; i < 3; ++i)
#pragma unroll
            for (int j = 0; j < 4; ++j) {
                acc[i][j] = MFMA16(ah[i], bh[j], acc[i][j]);
                acc[i][j] = MFMA16(ah[i], bl[j], acc[i][j]);
                acc[i][j] = MFMA16(al[i], bh[j], acc[i][j]);
            }
    }

    // ---- epilogue: C/D layout col=lane&15, row=(lane>>4)*4+r ----
    const int rr = (lane >> 4) * 4;
#pragma unroll
    for (int i = 0; i < 3; ++i)
#pragma unroll
        for (int j = 0; j < 4; ++j) {
            const int n = n0 + j * 16 + (lane & 15);
#pragma unroll
            for (int r = 0; r < 4; ++r) {
                const int mm = mw + i * 16 + rr + r;
                const float v = acc[i][j][r];
                if (SPLITOUT) {
                    if (mm < 384)
                        qk_out[(size_t)z * 384 * HWDIM + (size_t)mm * HWDIM + n] = f2bf(v);
                    else
                        v_out[(size_t)z * CDIM * HWDIM + (size_t)(mm - 384) * HWDIM + n] = v;
                } else {
                    plain[(size_t)z * CDIM * HWDIM + (size_t)mm * HWDIM + n] = v;
                }
            }
        }
}

// ---------------------------------------------------------------------------
// Depthwise 3x3 SAME, vectorized: block = (channel, 16-row tile, z).
// 256 thr: stage 18 rows x 256 cols (+halo) fp32 in LDS; each thread computes
// a 4x4 output tile. BF: bf16 in/out. F32: fp32 in/out.
// ---------------------------------------------------------------------------
template<bool BF>
__global__ __launch_bounds__(256) void dw3x3(
    const void* __restrict__ in_,    // [z][CH][256][256]
    const float* __restrict__ wdw,   // [CH][9]
    void* __restrict__ out_, int nch)
{
    __shared__ float rows[18][264];   // data cols 4..259; halo zeros at 3, 260
    const int t  = threadIdx.x;
    const int ch = blockIdx.x;
    const int y0 = blockIdx.y * 16;
    const int z  = blockIdx.z;
    const size_t base = ((size_t)z * nch + ch) * HWDIM;

    // stage 18 rows x 64 x 4 cols
    for (int idx = t; idx < 18 * 64; idx += 256) {
        const int row = idx >> 6;
        const int c4  = (idx & 63) << 2;
        const int y   = y0 - 1 + row;
        float4 v = {0.f, 0.f, 0.f, 0.f};
        if (y >= 0 && y < IMGW) {
            if (BF) {
                const ushort* p = (const ushort*)in_ + base + (size_t)y * IMGW + c4;
                ushort4 u = *(const ushort4*)p;
                v.x = bf2f(u.x); v.y = bf2f(u.y); v.z = bf2f(u.z); v.w = bf2f(u.w);
            } else {
                v = *(const float4*)((const float*)in_ + base + (size_t)y * IMGW + c4);
            }
        }
        *(float4*)&rows[row][4 + c4] = v;
    }
    if (t < 18) { rows[t][3] = 0.f; rows[t][260] = 0.f; }
    __syncthreads();

    float w[9];
#pragma unroll
    for (int i = 0; i < 9; ++i) w[i] = wdw[ch * 9 + i];

    const int rg = t >> 6;        // 0..3 -> 4 output rows
    const int cg = t & 63;        // 4 output cols
    float win[6][6];
#pragma unroll
    for (int r6 = 0; r6 < 6; ++r6) {
        const int row = rg * 4 + r6;
        float4 mid = *(const float4*)&rows[row][4 + cg * 4];
        win[r6][0] = rows[row][3 + cg * 4];
        win[r6][1] = mid.x; win[r6][2] = mid.y; win[r6][3] = mid.z; win[r6][4] = mid.w;
        win[r6][5] = rows[row][8 + cg * 4];
    }
#pragma unroll
    for (int rr = 0; rr < 4; ++rr) {
        float o[4];
#pragma unroll
        for (int cc = 0; cc < 4; ++cc) {
            float s = 0.f;
#pragma unroll
            for (int dy = 0; dy < 3; ++dy)
#pragma unroll
                for (int dx = 0; dx < 3; ++dx)
                    s = fmaf(win[rr + dy][cc + dx], w[dy * 3 + dx], s);
            o[cc] = s;
        }
        const size_t oo = base + (size_t)(y0 + rg * 4 + rr) * IMGW + cg * 4;
        if (BF) {
            ushort4 u;
            u.x = f2bf(o[0]); u.y = f2bf(o[1]); u.z = f2bf(o[2]); u.w = f2bf(o[3]);
            *(ushort4*)((ushort*)out_ + oo) = u;
        } else {
            *(float4*)((float*)out_ + oo) = make_float4(o[0], o[1], o[2], o[3]);
        }
    }
}

// ---------------------------------------------------------------------------
// Gram via MFMA (plain bf16): S[d][e] = sum_n q[d,n]*k[e,n], plus row norms.
// grid(32 chunks, 4 heads, z), 256 thr. Sb per head: [48*48 S][48 nq][48 nk]
// ---------------------------------------------------------------------------
__global__ __launch_bounds__(256) void gram_mfma(
    const ushort* __restrict__ qk,   // [z][384][HWDIM] bf16 (post-dw)
    float* __restrict__ Sb)          // [z][4][2400]
{
    const int h = blockIdx.y;
    const int z = blockIdx.z;
    const int lane = threadIdx.x & 63;
    const int wave = threadIdx.x >> 6;
    const int nbase = blockIdx.x * 2048 + wave * 512;
    const ushort* q0  = qk + (size_t)z * 384 * HWDIM + (size_t)(h * HDIM) * HWDIM;
    const ushort* k0p = q0 + (size_t)CDIM * HWDIM;
    const int ar = lane & 15;
    const int kg = (lane >> 4) * 8;

    f32x4 acc[3][3];
#pragma unroll
    for (int i = 0; i < 3; ++i)
#pragma unroll
        for (int j = 0; j < 3; ++j) { f32x4 zz = {0.f, 0.f, 0.f, 0.f}; acc[i][j] = zz; }
    float sq[3] = {0.f, 0.f, 0.f}, sk[3] = {0.f, 0.f, 0.f};

    for (int ks = 0; ks < 512; ks += 32) {
        const int n = nbase + ks + kg;
        short8 qa[3], ka[3];
#pragma unroll
        for (int i = 0; i < 3; ++i) {
            qa[i] = *reinterpret_cast<const short8*>(q0  + (size_t)(i * 16 + ar) * HWDIM + n);
            ka[i] = *reinterpret_cast<const short8*>(k0p + (size_t)(i * 16 + ar) * HWDIM + n);
        }
#pragma unroll
        for (int i = 0; i < 3; ++i)
#pragma unroll
            for (int e = 0; e < 8; ++e) {
                float fq = bf2f((ushort)qa[i][e]);
                float fk = bf2f((ushort)ka[i][e]);
                sq[i] = fmaf(fq, fq, sq[i]);
                sk[i] = fmaf(fk, fk, sk[i]);
            }
#pragma unroll
        for (int i = 0; i < 3; ++i)
#pragma unroll
            for (int j = 0; j < 3; ++j)
                acc[i][j] = MFMA16(qa[i], ka[j], acc[i][j]);
    }

    __shared__ float S_l[2400];
    for (int t = threadIdx.x; t < 2400; t += 256) S_l[t] = 0.f;
    __syncthreads();
    const int rr = (lane >> 4) * 4;
#pragma unroll
    for (int i = 0; i < 3; ++i)
#pragma unroll
        for (int j = 0; j < 3; ++j)
#pragma unroll
            for (int r = 0; r < 4; ++r)
                atomicAdd(&S_l[(i * 16 + rr + r) * 48 + (j * 16 + ar)], acc[i][j][r]);
#pragma unroll
    for (int i = 0; i < 3; ++i) {
        sq[i] += __shfl_xor(sq[i], 16); sq[i] += __shfl_xor(sq[i], 32);
        sk[i] += __shfl_xor(sk[i], 16); sk[i] += __shfl_xor(sk[i], 32);
    }
    if ((lane >> 4) == 0) {
#pragma unroll
        for (int i = 0; i < 3; ++i) {
            atomicAdd(&S_l[2304 + i * 16 + ar], sq[i]);
            atomicAdd(&S_l[2352 + i * 16 + ar], sk[i]);
        }
    }
    __syncthreads();
    float* Sg = Sb + (size_t)z * 4 * 2400 + h * 2400;
    for (int t = threadIdx.x; t < 2400; t += 256) atomicAdd(&Sg[t], S_l[t]);
}

// ---------------------------------------------------------------------------
// Normalize Gram, softmax over e, fold proj into W2 (bf16 hi/lo out).
// grid(4 co-blocks, z). All blocks recompute attn (cheap).
// ---------------------------------------------------------------------------
__global__ __launch_bounds__(256) void attn_w2(
    const float* __restrict__ S_all, // [z][4][2400]
    const float* __restrict__ proj,  // [192][192]
    const float* __restrict__ temp,  // [4]
    ushort* __restrict__ W2hi,       // [z][192][192]
    ushort* __restrict__ W2lo)
{
    __shared__ float attn[NHEADS][HDIM][HDIM];
    __shared__ float nqs[NHEADS][HDIM], nks[NHEADS][HDIM];
    const int t = threadIdx.x;
    const int co0 = blockIdx.x * 48;
    const int z = blockIdx.y;
    const float* S = S_all + (size_t)z * 4 * 2400;
    ushort* w2h = W2hi + (size_t)z * CDIM * CDIM;
    ushort* w2l = W2lo + (size_t)z * CDIM * CDIM;

    for (int idx = t; idx < NHEADS * 96; idx += 256) {
        const int h = idx / 96, r = idx % 96;
        float v = sqrtf(S[h * 2400 + 2304 + r]);
        v = fmaxf(v, 1e-12f);
        if (r < 48) nqs[h][r] = v; else nks[h][r - 48] = v;
    }
    __syncthreads();
    if (t < NHEADS * HDIM) {
        const int h = t / HDIM, d = t % HDIM;
        const float tp  = temp[h];
        const float inq = 1.0f / nqs[h][d];
        float row[48];
        float mx = -1e30f;
#pragma unroll
        for (int e = 0; e < 48; ++e) {
            row[e] = S[h * 2400 + d * 48 + e] * inq / nks[h][e] * tp;
            mx = fmaxf(mx, row[e]);
        }
        float sum = 0.f;
#pragma unroll
        for (int e = 0; e < 48; ++e) { row[e] = expf(row[e] - mx); sum += row[e]; }
        const float isum = 1.0f / sum;
#pragma unroll
        for (int e = 0; e < 48; ++e) attn[h][d][e] = row[e] * isum;
    }
    __syncthreads();
    for (int idx = t; idx < 48 * 192; idx += 256) {
        const int co = co0 + idx / 192, he = idx % 192;
        const int h = he / 48, e = he % 48;
        const float* pr = proj + co * 192 + h * 48;
        float s = 0.f;
#pragma unroll
        for (int d = 0; d < 48; ++d) s = fmaf(pr[d], attn[h][d][e], s);
        ushort hh = f2bf(s);
        w2h[co * 192 + he] = hh;
        w2l[co * 192 + he] = f2bf(s - bf2f(hh));
    }
}

__global__ void zerof(float* __restrict__ p, int n)
{
    const int i = blockIdx.x * 256 + threadIdx.x;
    if (i < n) p[i] = 0.f;
}

// ---------------------------------------------------------------------------
extern "C" void kernel_launch(void* const* d_in, const int* in_sizes, int n_in,
                              void* d_out, int out_size, void* d_ws, size_t ws_size,
                              hipStream_t stream)
{
    const float* x      = (const float*)d_in[0];  // [4][192][65536]
    const float* qkv_w  = (const float*)d_in[1];  // [576][192]
    const float* dw_w   = (const float*)d_in[2];  // [576][9]
    const float* proj_w = (const float*)d_in[3];  // [192][192]
    const float* temp   = (const float*)d_in[4];  // [4]
    float* out = (float*)d_out;

    char* w = (char*)d_ws;
    ushort* qk_pre = (ushort*)w;  w += (size_t)ZPAIR * 384 * HWDIM * 2;   // 100.7 MB
    float*  v_pre  = (float*)w;   w += (size_t)ZPAIR * CDIM * HWDIM * 4;  // 100.7 MB
    ushort* qk_dw  = (ushort*)w;  w += (size_t)ZPAIR * 384 * HWDIM * 2;   // 100.7 MB
    float*  v_dw   = (float*)w;   w += (size_t)ZPAIR * CDIM * HWDIM * 4;  // 100.7 MB
    ushort* A1hi   = (ushort*)w;  w += (size_t)576 * 192 * 2;
    ushort* A1lo   = (ushort*)w;  w += (size_t)576 * 192 * 2;
    ushort* W2hi   = (ushort*)w;  w += (size_t)ZPAIR * CDIM * CDIM * 2;
    ushort* W2lo   = (ushort*)w;  w += (size_t)ZPAIR * CDIM * CDIM * 2;
    float*  S_all  = (float*)w;   w += (size_t)BATCH * 4 * 2400 * 4;

    zerof<<<150, 256, 0, stream>>>(S_all, BATCH * 4 * 2400);
    wsplit<<<(576 * 192 + 255) / 256, 256, 0, stream>>>(qkv_w, A1hi, A1lo, 576 * 192);

    for (int p = 0; p < BATCH / ZPAIR; ++p) {
        const float* xp = x   + (size_t)p * ZPAIR * CDIM * HWDIM;
        float*       op = out + (size_t)p * ZPAIR * CDIM * HWDIM;
        float*       Sp = S_all + (size_t)p * ZPAIR * 4 * 2400;

        // 1) qkv 1x1 conv (bf16x3 MFMA, swizzled LDS staging)
        gemm_staged<true><<<dim3(1024, 3, ZPAIR), 256, 0, stream>>>(
            A1hi, A1lo, xp, qk_pre, v_pre, nullptr, 0);
        // 2) depthwise 3x3 (vectorized)
        dw3x3<true> <<<dim3(384, 16, ZPAIR), 256, 0, stream>>>(qk_pre, dw_w, qk_dw, 384);
        dw3x3<false><<<dim3(192, 16, ZPAIR), 256, 0, stream>>>(v_pre, dw_w + 384 * 9, v_dw, 192);
        // 3) Gram + norms (bf16 MFMA)
        gram_mfma<<<dim3(32, 4, ZPAIR), 256, 0, stream>>>(qk_dw, Sp);
        // 4) softmax + fold projection
        attn_w2<<<dim3(4, ZPAIR), 256, 0, stream>>>(Sp, proj_w, temp, W2hi, W2lo);
        // 5) out = W2 @ v (bf16x3 MFMA)
        gemm_staged<false><<<dim3(1024, 1, ZPAIR), 256, 0, stream>>>(
            W2hi, W2lo, v_dw, nullptr, nullptr, op, CDIM * CDIM);
    }
}